// Round 6
// baseline (277.048 us; speedup 1.0000x reference)
//
#include <hip/hip_runtime.h>
#include <math.h>

#define NQ    8192
#define NPTS  32768
#define KNN   64
#define GRIDD 16
#define NCELL 4096          // 16^3 cells, h=0.5 over [-4,4)
#define CAP   224           // per-query candidate capacity (E=110)
#define NBLKM 2048          // main kernel blocks (4 queries each)

// ---- ws layout (4B elements) ----
#define WS_START 0          // 4097
#define WS_X     4100       // 32768 (16B-aligned: 4100*4=16400, /16 ok)
#define WS_Y     36868
#define WS_Z     69636
#define WS_I     102404
#define WS_TOT_C 135172     // tier C total (540,688 B)
#define WS_QX    135172     // 8192
#define WS_QY    143364
#define WS_QZ    151556
#define WS_QI    159748
#define WS_FS    167940     // 4,194,304 (byte off 671,760, 16B-aligned)
#define WS_TOT_A 4362244    // tier A total (~17.45 MB)

__device__ __forceinline__ int mbcnt64(unsigned long long m) {
  return __builtin_amdgcn_mbcnt_hi((unsigned)(m >> 32),
         __builtin_amdgcn_mbcnt_lo((unsigned)m, 0));
}
__device__ __forceinline__ int cell1(float v) {
  int c = (int)floorf((v + 4.f) * 2.f);
  return min(GRIDD - 1, max(0, c));
}

// ============ K_prep: single block, 1024 threads ============
// zero+count+scan+scatter for points (always) and queries (doQ).
__global__ __launch_bounds__(1024) void k_prep(
    const float* __restrict__ pos, const float* __restrict__ qpos,
    int* __restrict__ start,
    float* __restrict__ X, float* __restrict__ Y, float* __restrict__ Z, int* __restrict__ I,
    float* __restrict__ QX, float* __restrict__ QY, float* __restrict__ QZ, int* __restrict__ QI,
    int doQ) {
  __shared__ int hist[NCELL];
  __shared__ int wsc[16];
  const int tid = threadIdx.x, lane = tid & 63, wv = tid >> 6;

  // ---- points: zero, count ----
  for (int i = tid; i < NCELL; i += 1024) hist[i] = 0;
  __syncthreads();
  for (int p = tid; p < NPTS; p += 1024) {
    float x = pos[3 * p], y = pos[3 * p + 1], z = pos[3 * p + 2];
    atomicAdd(&hist[(cell1(z) * GRIDD + cell1(y)) * GRIDD + cell1(x)], 1);
  }
  __syncthreads();
  // ---- scan (4 cells/thread) ----
  {
    int l0 = hist[tid * 4], l1 = hist[tid * 4 + 1], l2 = hist[tid * 4 + 2], l3 = hist[tid * 4 + 3];
    int s = l0 + l1 + l2 + l3, sc = s;
    #pragma unroll
    for (int d = 1; d < 64; d <<= 1) { int t = __shfl_up(sc, d, 64); if (lane >= d) sc += t; }
    if (lane == 63) wsc[wv] = sc;
    __syncthreads();
    int wpre = 0;
    for (int w = 0; w < wv; ++w) wpre += wsc[w];
    int excl = wpre + sc - s;
    start[tid * 4] = excl; start[tid * 4 + 1] = excl + l0;
    start[tid * 4 + 2] = excl + l0 + l1; start[tid * 4 + 3] = excl + l0 + l1 + l2;
    if (tid == 1023) start[NCELL] = excl + s;
    __syncthreads();
    hist[tid * 4] = excl; hist[tid * 4 + 1] = excl + l0;
    hist[tid * 4 + 2] = excl + l0 + l1; hist[tid * 4 + 3] = excl + l0 + l1 + l2;
  }
  __syncthreads();
  // ---- scatter points ----
  for (int p = tid; p < NPTS; p += 1024) {
    float x = pos[3 * p], y = pos[3 * p + 1], z = pos[3 * p + 2];
    int c = (cell1(z) * GRIDD + cell1(y)) * GRIDD + cell1(x);
    int j = atomicAdd(&hist[c], 1);
    X[j] = x; Y[j] = y; Z[j] = z; I[j] = p;
  }
  if (!doQ) return;
  __syncthreads();
  // ---- queries: zero, count, scan, scatter ----
  for (int i = tid; i < NCELL; i += 1024) hist[i] = 0;
  __syncthreads();
  for (int q = tid; q < NQ; q += 1024) {
    float x = qpos[3 * q], y = qpos[3 * q + 1], z = qpos[3 * q + 2];
    atomicAdd(&hist[(cell1(z) * GRIDD + cell1(y)) * GRIDD + cell1(x)], 1);
  }
  __syncthreads();
  {
    int l0 = hist[tid * 4], l1 = hist[tid * 4 + 1], l2 = hist[tid * 4 + 2], l3 = hist[tid * 4 + 3];
    int s = l0 + l1 + l2 + l3, sc = s;
    #pragma unroll
    for (int d = 1; d < 64; d <<= 1) { int t = __shfl_up(sc, d, 64); if (lane >= d) sc += t; }
    __syncthreads();                 // wsc reuse safety
    if (lane == 63) wsc[wv] = sc;
    __syncthreads();
    int wpre = 0;
    for (int w = 0; w < wv; ++w) wpre += wsc[w];
    int excl = wpre + sc - s;
    __syncthreads();                 // all hist reads done before overwrite
    hist[tid * 4] = excl; hist[tid * 4 + 1] = excl + l0;
    hist[tid * 4 + 2] = excl + l0 + l1; hist[tid * 4 + 3] = excl + l0 + l1 + l2;
  }
  __syncthreads();
  for (int q = tid; q < NQ; q += 1024) {
    float x = qpos[3 * q], y = qpos[3 * q + 1], z = qpos[3 * q + 2];
    int c = (cell1(z) * GRIDD + cell1(y)) * GRIDD + cell1(x);
    int j = atomicAdd(&hist[c], 1);
    QX[j] = x; QY[j] = y; QZ[j] = z; QI[j] = q;
  }
}

// ============ K_reorder: FS[j] = feat[I[j]] (512 blocks x 256) ============
__global__ void k_reorder(const float* __restrict__ feat, const int* __restrict__ I,
                          float* __restrict__ FS) {
  const int j = blockIdx.x * 64 + (threadIdx.x >> 2);
  const int part = threadIdx.x & 3;
  const float4* src = (const float4*)(feat + ((size_t)I[j] << 7));
  float4* dst = (float4*)(FS + ((size_t)j << 7));
  #pragma unroll
  for (int c = part; c < 32; c += 4) dst[c] = src[c];
}

// ============ K_main: one wave per query ============
template<bool SF>
__global__ __launch_bounds__(256, 8) void k_main(
    const float* __restrict__ qpos, const float* __restrict__ feat,
    const float* __restrict__ FS, const int* __restrict__ start,
    const float* __restrict__ X, const float* __restrict__ Y, const float* __restrict__ Z,
    const int* __restrict__ I,
    const float* __restrict__ QX, const float* __restrict__ QY, const float* __restrict__ QZ,
    const int* __restrict__ QI, float* __restrict__ out) {

  __shared__ uint2 sCand[4][CAP];
  __shared__ uint2 sSel[4][KNN];

  const int tid = threadIdx.x, lane = tid & 63, wv = tid >> 6;
  // XCD swizzle: consecutive sorted-query ranges per XCD (L2 locality)
  const int vb = SF ? ((blockIdx.x & 7) * (NBLKM / 8) + (blockIdx.x >> 3)) : blockIdx.x;
  const int qs = vb * 4 + wv;

  float qx, qy, qz; int gq;
  if (SF) { qx = QX[qs]; qy = QY[qs]; qz = QZ[qs]; gq = QI[qs]; }
  else    { gq = qs; qx = qpos[3 * gq]; qy = qpos[3 * gq + 1]; qz = qpos[3 * gq + 2]; }

  // ---- tau from local-density model: E[count in ball r] ~ 110 ----
  const float mu2 = qx * qx + qy * qy + qz * qz;
  float tau;
  {
    const float rho = 0.06349363f * __expf(-0.5f * mu2);      // (2pi)^{-3/2} e^{-mu^2/2}
    const float base = 110.f / ((float)NPTS * rho * 4.18879f); // r^3 estimate
    const float r0 = cbrtf(base);
    float corr = fmaxf(1.f + r0 * r0 * (mu2 - 3.f) * 0.1f, 0.3f);
    const float r = r0 * cbrtf(1.f / corr);
    tau = r * r;
  }
  float tlo = 0.f, thi = -1.f;
  int m = 0;

  // ---- candidate collection over grid cells ----
  for (int attempt = 0; attempt < 16; ++attempt) {
    m = 0;
    const float r = sqrtf(tau);
    const int xlo = cell1(qx - r), xhi = cell1(qx + r);
    const int ylo = cell1(qy - r), yhi = cell1(qy + r);
    const int zlo = cell1(qz - r), zhi = cell1(qz + r);
    for (int cz = zlo; cz <= zhi; ++cz) {
      for (int cy = ylo; cy <= yhi; ++cy) {
        const int row = (cz * GRIDD + cy) * GRIDD;
        const int rs = start[row + xlo];
        const int re = start[row + xhi + 1];
        for (int j0 = rs; j0 < re; j0 += 64) {
          const int j = j0 + lane;
          float d = 3.4e38f;
          if (j < re) {
            float dx = X[j] - qx, dy = Y[j] - qy, dz = Z[j] - qz;
            d = fmaf(dx, dx, fmaf(dy, dy, dz * dz));
          }
          const bool h = d < tau;
          const unsigned long long msk = __ballot(h);
          if (msk) {
            const int p = m + mbcnt64(msk);
            if (h && p < CAP) {
              const unsigned pid = SF ? (unsigned)j : (unsigned)I[j];
              sCand[wv][p] = make_uint2(__float_as_uint(d), pid);
            }
            m += (int)__popcll(msk);
          }
        }
      }
    }
    if (m >= KNN && m <= CAP) break;
    if (m < KNN) { tlo = tau; tau = (thi < 0.f) ? tau * 2.5f : 0.5f * (tau + thi); }
    else         { thi = tau; tau = 0.5f * (tlo + tau); }
  }

  // ---- exact top-64 (bisection on nonneg float bits) ----
  const int mm = min(m, CAP);
  const int NS = (mm + 63) >> 6;
  unsigned k[4], id[4];
  #pragma unroll
  for (int s = 0; s < 4; ++s) {
    k[s] = 0xFFFFFFFFu; id[s] = 0u;
    if (s < NS) {
      const int g = s * 64 + lane;
      if (g < mm) { uint2 kv = sCand[wv][g]; k[s] = kv.x; id[s] = kv.y; }
    }
  }
  sSel[wv][lane] = make_uint2(0u, 0u);   // padding: id 0, w 0

  if (mm > KNN) {
    unsigned lo = 0u, hi = __float_as_uint(tau);
    while (lo < hi) {
      const unsigned mid = lo + ((hi - lo) >> 1);
      int c = 0;
      #pragma unroll
      for (int s = 0; s < 4; ++s)
        if (s < NS) c += (int)__popcll(__ballot(k[s] <= mid));
      if (c >= KNN) hi = mid; else lo = mid + 1;
    }
    const unsigned K = lo;
    int fill = 0;
    #pragma unroll
    for (int s = 0; s < 4; ++s) {
      if (s < NS) {
        const bool lt = k[s] < K;
        const unsigned long long msk = __ballot(lt);
        if (msk) {
          const int p = fill + mbcnt64(msk);
          if (lt) {
            float dv = __uint_as_float(k[s]);
            float w_ = 1.f / (sqrtf(fmaxf(dv, 1e-12f)) + 1e-5f);
            sSel[wv][p] = make_uint2(id[s], __float_as_uint(w_));
          }
          fill += (int)__popcll(msk);
        }
      }
    }
    #pragma unroll
    for (int s = 0; s < 4; ++s) {
      if (s < NS) {
        const bool eq = (k[s] == K);
        const unsigned long long msk = __ballot(eq);
        if (msk) {
          const int p = fill + mbcnt64(msk);
          if (eq && p < KNN) {
            float dv = __uint_as_float(k[s]);
            float w_ = 1.f / (sqrtf(fmaxf(dv, 1e-12f)) + 1e-5f);
            sSel[wv][p] = make_uint2(id[s], __float_as_uint(w_));
          }
          fill += (int)__popcll(msk);
        }
      }
    }
  } else {
    #pragma unroll
    for (int s = 0; s < 4; ++s) {
      if (s < NS) {
        const int g = s * 64 + lane;
        if (g < mm) {
          float dv = __uint_as_float(k[s]);
          float w_ = 1.f / (sqrtf(fmaxf(dv, 1e-12f)) + 1e-5f);
          sSel[wv][g] = make_uint2(id[s], __float_as_uint(w_));
        }
      }
    }
  }

  // ---- gather: float4/lane, 2 rows per iter, shfl-combine halves ----
  const float* FB = SF ? FS : feat;
  const int half = lane >> 5;        // 0: even slots, 1: odd slots
  const int c4 = lane & 31;          // float4 column
  float4 acc = make_float4(0.f, 0.f, 0.f, 0.f);
  #pragma unroll 4
  for (int jj = 0; jj < 32; ++jj) {
    const uint2 pr = sSel[wv][(jj << 1) + half];
    const float w = __uint_as_float(pr.y);
    const float4 f = *(const float4*)(FB + ((size_t)pr.x << 7) + (c4 << 2));
    acc.x = fmaf(w, f.x, acc.x); acc.y = fmaf(w, f.y, acc.y);
    acc.z = fmaf(w, f.z, acc.z); acc.w = fmaf(w, f.w, acc.w);
  }
  const float ox = acc.x + __shfl_xor(acc.x, 32, 64);
  const float oy = acc.y + __shfl_xor(acc.y, 32, 64);
  const float oz = acc.z + __shfl_xor(acc.z, 32, 64);
  const float ow = acc.w + __shfl_xor(acc.w, 32, 64);
  if (lane < 32) {
    float4 o = make_float4(ox, oy, oz, ow);
    *(float4*)(out + ((size_t)gq << 7) + (c4 << 2)) = o;
  }
}

extern "C" void kernel_launch(void* const* d_in, const int* in_sizes, int n_in,
                              void* d_out, int out_size, void* d_ws, size_t ws_size,
                              hipStream_t stream) {
  const float* qpos = (const float*)d_in[0];   // [8192,3]
  const float* feat = (const float*)d_in[1];   // [32768,128]
  const float* pos  = (const float*)d_in[2];   // [32768,3]
  float* out = (float*)d_out;                  // [8192,128]

  float* wsf = (float*)d_ws;
  int*   wsi = (int*)d_ws;
  int*   start = wsi + WS_START;
  float* X = wsf + WS_X; float* Y = wsf + WS_Y; float* Z = wsf + WS_Z;
  int*   I = wsi + WS_I;

  if (ws_size >= (size_t)WS_TOT_A * 4) {
    float* QX = wsf + WS_QX; float* QY = wsf + WS_QY; float* QZ = wsf + WS_QZ;
    int*   QI = wsi + WS_QI;
    float* FS = wsf + WS_FS;
    k_prep<<<dim3(1), dim3(1024), 0, stream>>>(pos, qpos, start, X, Y, Z, I, QX, QY, QZ, QI, 1);
    k_reorder<<<dim3(NPTS / 64), dim3(256), 0, stream>>>(feat, I, FS);
    k_main<true><<<dim3(NBLKM), dim3(256), 0, stream>>>(qpos, feat, FS, start, X, Y, Z, I,
                                                        QX, QY, QZ, QI, out);
  } else {
    k_prep<<<dim3(1), dim3(1024), 0, stream>>>(pos, qpos, start, X, Y, Z, I,
                                               nullptr, nullptr, nullptr, nullptr, 0);
    k_main<false><<<dim3(NBLKM), dim3(256), 0, stream>>>(qpos, feat, nullptr, start, X, Y, Z, I,
                                                         nullptr, nullptr, nullptr, nullptr, out);
  }
}